// Round 13
// baseline (123.036 us; speedup 1.0000x reference)
//
#include <hip/hip_runtime.h>
#include <hip/hip_bf16.h>

typedef __attribute__((ext_vector_type(8))) short short8;
typedef __attribute__((ext_vector_type(4))) short short4v;
typedef __attribute__((ext_vector_type(8))) _Float16 half8;
typedef __attribute__((ext_vector_type(4))) float f32x4;

#define SPW 16384   // T*H*W spatial positions per batch
#define XST 72      // Xl row stride in shorts
#define RW  67      // Rf row stride in dwords
#define LOG2E 1.4426950408889634f

__device__ __forceinline__ float exp2_hw(float f) {
  return __builtin_amdgcn_exp2f(f);   // v_exp_f32 (base-2)
}

__device__ __forceinline__ short bf16s(float f) {
  union { __hip_bfloat16 h; short s; } u;
  u.h = __float2bfloat16(f);
  return u.s;
}

// ---------------- merged prep kernel ----------------
// a1b[(kt*64+lane)*2+s] : A-frags (16x16x32 bf16) of (-2*log2e)*E, pair contiguous
// eb3[(pr*64+lane)*4+m2]: B-frags (16x16x32 f16) of E for a kt-PAIR; slot i<4 ->
//                         k=(2pr)*16+4g+i, i>=4 -> k=(2pr+1)*16+4g+(i-4)
// norms[k]              : ||e_k||^2 * log2e
__global__ void prep_all(const float* __restrict__ emb, short8* __restrict__ a1b,
                         half8* __restrict__ eb3, float* __restrict__ norms) {
  const int f = blockIdx.x * 256 + threadIdx.x;
  if (f < 4096) {
    const int s = f & 1;
    const int lane = (f >> 1) & 63;
    const int kt = f >> 7;
    const int row = kt * 16 + (lane & 15);
    const int col0 = s * 32 + (lane >> 4) * 8;
    short8 v;
    #pragma unroll
    for (int i = 0; i < 8; ++i)
      v[i] = bf16s(-2.0f * LOG2E * emb[row * 64 + col0 + i]);
    a1b[f] = v;
  } else if (f < 8192) {
    const int e = f - 4096;
    const int m2 = e & 3;
    const int lane = (e >> 2) & 63;
    const int pr = e >> 8;               // kt-pair 0..15
    const int g = lane >> 4;
    const int d = m2 * 16 + (lane & 15);
    half8 v;
    #pragma unroll
    for (int i = 0; i < 8; ++i) {
      const int k = (i < 4) ? (pr * 32 + 4 * g + i) : (pr * 32 + 16 + 4 * g + (i - 4));
      v[i] = (_Float16)emb[k * 64 + d];
    }
    eb3[e] = v;
  } else if (f < 8704) {
    const int k = f - 8192;
    float acc = 0.f;
    #pragma unroll
    for (int d = 0; d < 64; ++d) { float e = emb[k * 64 + d]; acc += e * e; }
    norms[k] = acc * LOG2E;
  }
}

// per-iteration fragment set (register double-buffered)
struct Frags {
  short8 aA0, aA1, aB0, aB1;
  half8 e0, e1, e2, e3;
  float4 nvA, nvB;
};

__device__ __forceinline__ void ldfrag(Frags& f, const short8* __restrict__ a1b,
                                       const half8* __restrict__ eb3,
                                       const float* __restrict__ norms,
                                       int pr, int lane, int g) {
  const int ktA = pr * 2;
  f.nvA = *reinterpret_cast<const float4*>(&norms[ktA * 16 + g * 4]);
  f.nvB = *reinterpret_cast<const float4*>(&norms[ktA * 16 + 16 + g * 4]);
  const short8* ap = &a1b[(ktA * 64 + lane) * 2];
  f.aA0 = ap[0];
  f.aA1 = ap[1];
  f.aB0 = ap[128];             // ktB = ktA+1 -> +64*2 short8
  f.aB1 = ap[129];
  const half8* ep = &eb3[(pr * 64 + lane) * 4];   // 64B contiguous
  f.e0 = ep[0];
  f.e1 = ep[1];
  f.e2 = ep[2];
  f.e3 = ep[3];
}

__device__ __forceinline__ half8 make_pa(float p0, float p1, float p2, float p3,
                                         float p4, float p5, float p6, float p7) {
  const unsigned a = __builtin_bit_cast(unsigned, __builtin_amdgcn_cvt_pkrtz(p0, p1));
  const unsigned b = __builtin_bit_cast(unsigned, __builtin_amdgcn_cvt_pkrtz(p2, p3));
  const unsigned c = __builtin_bit_cast(unsigned, __builtin_amdgcn_cvt_pkrtz(p4, p5));
  const unsigned d = __builtin_bit_cast(unsigned, __builtin_amdgcn_cvt_pkrtz(p6, p7));
  const uint4 u = {a, b, c, d};
  return __builtin_bit_cast(half8, u);
}

__device__ __forceinline__ void compute_unit(const Frags& f, const short8 bx[4][2],
                                             f32x4 pacc[4][4], f32x4 dacc[4],
                                             const half8 ones) {
  #pragma unroll
  for (int j = 0; j < 4; ++j) {
    f32x4 zA = {f.nvA.x, f.nvA.y, f.nvA.z, f.nvA.w};   // norm term as C-init
    zA = __builtin_amdgcn_mfma_f32_16x16x32_bf16(f.aA0, bx[j][0], zA, 0, 0, 0);
    zA = __builtin_amdgcn_mfma_f32_16x16x32_bf16(f.aA1, bx[j][1], zA, 0, 0, 0);
    f32x4 zB = {f.nvB.x, f.nvB.y, f.nvB.z, f.nvB.w};
    zB = __builtin_amdgcn_mfma_f32_16x16x32_bf16(f.aB0, bx[j][0], zB, 0, 0, 0);
    zB = __builtin_amdgcn_mfma_f32_16x16x32_bf16(f.aB1, bx[j][1], zB, 0, 0, 0);
    const float p0 = exp2_hw(zA[0]);
    const float p1 = exp2_hw(zA[1]);
    const float p2 = exp2_hw(zA[2]);
    const float p3 = exp2_hw(zA[3]);
    const float p4 = exp2_hw(zB[0]);
    const float p5 = exp2_hw(zB[1]);
    const float p6 = exp2_hw(zB[2]);
    const float p7 = exp2_hw(zB[3]);
    const half8 pa = make_pa(p0, p1, p2, p3, p4, p5, p6, p7);
    pacc[j][0] = __builtin_amdgcn_mfma_f32_16x16x32_f16(pa, f.e0, pacc[j][0], 0, 0, 0);
    pacc[j][1] = __builtin_amdgcn_mfma_f32_16x16x32_f16(pa, f.e1, pacc[j][1], 0, 0, 0);
    pacc[j][2] = __builtin_amdgcn_mfma_f32_16x16x32_f16(pa, f.e2, pacc[j][2], 0, 0, 0);
    pacc[j][3] = __builtin_amdgcn_mfma_f32_16x16x32_f16(pa, f.e3, pacc[j][3], 0, 0, 0);
    // den: ones-MFMA -> dacc[j][r] = den[n=j*16+4g+r] (replicated over l15)
    dacc[j] = __builtin_amdgcn_mfma_f32_16x16x32_f16(pa, ones, dacc[j], 0, 0, 0);
  }
}

__device__ __forceinline__ void ldx(float4 xr[8], const float* __restrict__ xb, int t) {
  const int n0 = 4 * (t & 15);
  const int d0 = 4 * (t >> 4);
  #pragma unroll
  for (int h = 0; h < 2; ++h) {
    const int nb = h * 64 + n0;
    #pragma unroll
    for (int i = 0; i < 4; ++i)
      xr[h * 4 + i] = *reinterpret_cast<const float4*>(xb + (size_t)(d0 + i) * SPW + nb);
  }
}

__device__ __forceinline__ void stx(const float4 xr[8], short* Xl, int t) {
  const int n0 = 4 * (t & 15);
  const int d0 = 4 * (t >> 4);
  #pragma unroll
  for (int h = 0; h < 2; ++h) {
    const int nb = h * 64 + n0;
    const float4 r0 = xr[h * 4 + 0];
    const float4 r1 = xr[h * 4 + 1];
    const float4 r2 = xr[h * 4 + 2];
    const float4 r3 = xr[h * 4 + 3];
    const short4v c0 = {bf16s(r0.x), bf16s(r1.x), bf16s(r2.x), bf16s(r3.x)};
    const short4v c1 = {bf16s(r0.y), bf16s(r1.y), bf16s(r2.y), bf16s(r3.y)};
    const short4v c2 = {bf16s(r0.z), bf16s(r1.z), bf16s(r2.z), bf16s(r3.z)};
    const short4v c3 = {bf16s(r0.w), bf16s(r1.w), bf16s(r2.w), bf16s(r3.w)};
    *reinterpret_cast<short4v*>(&Xl[(nb + 0) * XST + d0]) = c0;
    *reinterpret_cast<short4v*>(&Xl[(nb + 1) * XST + d0]) = c1;
    *reinterpret_cast<short4v*>(&Xl[(nb + 2) * XST + d0]) = c2;
    *reinterpret_cast<short4v*>(&Xl[(nb + 3) * XST + d0]) = c3;
  }
}

// ---------------- main kernel ----------------
// Persistent: 512 blocks (2/CU resident, no generations), each runs 2 tiles of
// 128 n-columns. Per tile: 4 waves, wave (cg,kg) owns cols [cg*64,+64) x
// k [kg*256,+256) as 8 kt-pairs (R11 structure, 38 us). Tile 1's X is loaded to
// registers right after tile 0's bx reads, hiding its HBM latency under tile 0's
// main loop (oldest vmcnt slots -> frag waits retire it for free).
__global__ __launch_bounds__(256, 2) void vq_main(
    const float* __restrict__ x, const short8* __restrict__ a1b,
    const half8* __restrict__ eb3, const float* __restrict__ norms,
    float* __restrict__ out) {
  __shared__ __align__(16) char lds_raw[35840];
  short* Xl   = reinterpret_cast<short*>(lds_raw);            // [128][72] bf16 (staging)
  float* Rf   = reinterpret_cast<float*>(lds_raw);            // [128][67] f32 (epilogue)
  float* denl = reinterpret_cast<float*>(lds_raw + 34304);    // [2][128]
  float* rden = reinterpret_cast<float*>(lds_raw + 35328);    // [128]

  const int t = threadIdx.x;
  const int lane = t & 63;
  const int w = t >> 6;
  const int cg = w & 1;        // column group (64 cols)
  const int kg = w >> 1;       // k group (8 kt-pairs)
  const int l15 = lane & 15;
  const int g = lane >> 4;
  const int prb = kg * 8;

  const half8 ones = {(_Float16)1.f, (_Float16)1.f, (_Float16)1.f, (_Float16)1.f,
                      (_Float16)1.f, (_Float16)1.f, (_Float16)1.f, (_Float16)1.f};

  float4 xr[8], xrn[8];
  {
    const int tile0 = blockIdx.x * 128;
    ldx(xr, x + (size_t)(tile0 >> 14) * (64 * SPW) + (tile0 & 16383), t);
  }

  #pragma unroll 1
  for (int tt = 0; tt < 2; ++tt) {
    const int tile = (blockIdx.x + tt * 512) * 128;
    float* ob = out + (size_t)(tile >> 14) * (64 * SPW) + (tile & 16383);

    // stage X tile from registers
    stx(xr, Xl, t);
    __syncthreads();

    // bx: matmul1 B-frags for this wave's 64 columns (32 VGPR)
    short8 bx[4][2];
    #pragma unroll
    for (int j = 0; j < 4; ++j) {
      const int base = (cg * 64 + j * 16 + l15) * XST + g * 8;
      bx[j][0] = *reinterpret_cast<const short8*>(&Xl[base]);
      bx[j][1] = *reinterpret_cast<const short8*>(&Xl[base + 32]);
    }
    __syncthreads();   // all Xl reads done before Rf (aliased) is written later

    // prefetch next tile's X into registers (hides under this tile's main loop)
    if (tt == 0) {
      const int tile1 = (blockIdx.x + 512) * 128;
      ldx(xrn, x + (size_t)(tile1 >> 14) * (64 * SPW) + (tile1 & 16383), t);
      __builtin_amdgcn_sched_barrier(0);   // keep these loads issued here
    }

    f32x4 pacc[4][4];
    #pragma unroll
    for (int j = 0; j < 4; ++j)
      #pragma unroll
      for (int m2 = 0; m2 < 4; ++m2) pacc[j][m2] = f32x4{0.f, 0.f, 0.f, 0.f};
    f32x4 dacc[4];
    #pragma unroll
    for (int j = 0; j < 4; ++j) dacc[j] = f32x4{0.f, 0.f, 0.f, 0.f};

    // main loop: 8 kt-pairs, register double-buffered
    Frags fA, fB;
    ldfrag(fA, a1b, eb3, norms, prb + 0, lane, g);
    #pragma unroll
    for (int p2 = 0; p2 < 4; ++p2) {
      ldfrag(fB, a1b, eb3, norms, prb + 2 * p2 + 1, lane, g);
      compute_unit(fA, bx, pacc, dacc, ones);
      if (p2 < 3) ldfrag(fA, a1b, eb3, norms, prb + 2 * p2 + 2, lane, g);
      compute_unit(fB, bx, pacc, dacc, ones);
    }

    // den partials -> denl[kg][col]; dacc[j][r] = den[n], uniform over l15
    if (l15 == 0) {
      #pragma unroll
      for (int j = 0; j < 4; ++j)
        #pragma unroll
        for (int r = 0; r < 4; ++r)
          denl[kg * 128 + cg * 64 + j * 16 + 4 * g + r] = dacc[j][r];
    }

    // phase A: kg==0 waves write their Num^T partial into Rf (Xl is dead)
    if (kg == 0) {
      #pragma unroll
      for (int j = 0; j < 4; ++j)
        #pragma unroll
        for (int m2 = 0; m2 < 4; ++m2)
          #pragma unroll
          for (int r = 0; r < 4; ++r)
            Rf[(cg * 64 + j * 16 + 4 * g + r) * RW + m2 * 16 + l15] = pacc[j][m2][r];
    }
    __syncthreads();   // denl complete; phase-A Rf writes complete

    // phase B: kg==1 waves accumulate; kg==0 threads (t<128) build reciprocal den
    if (kg == 1) {
      #pragma unroll
      for (int j = 0; j < 4; ++j)
        #pragma unroll
        for (int m2 = 0; m2 < 4; ++m2)
          #pragma unroll
          for (int r = 0; r < 4; ++r)
            Rf[(cg * 64 + j * 16 + 4 * g + r) * RW + m2 * 16 + l15] += pacc[j][m2][r];
    } else {
      rden[t & 127] = 1.0f / (denl[t & 127] + denl[128 + (t & 127)]);
    }
    __syncthreads();

    // phase C: cooperative store, 512B contiguous per d-row (32 lanes x float4)
    const int nq = t & 31;
    const int n = 4 * nq;
    const int dh = t >> 5;
    #pragma unroll
    for (int it = 0; it < 8; ++it) {
      const int d = it * 8 + dh;
      const float4 o = {Rf[(n + 0) * RW + d] * rden[n + 0],
                        Rf[(n + 1) * RW + d] * rden[n + 1],
                        Rf[(n + 2) * RW + d] * rden[n + 2],
                        Rf[(n + 3) * RW + d] * rden[n + 3]};
      *reinterpret_cast<float4*>(&ob[(size_t)d * SPW + n]) = o;
    }
    __syncthreads();   // Rf reads done before next tile's staging overwrites Xl

    #pragma unroll
    for (int i = 0; i < 8; ++i) xr[i] = xrn[i];
  }
}

extern "C" void kernel_launch(void* const* d_in, const int* in_sizes, int n_in,
                              void* d_out, int out_size, void* d_ws, size_t ws_size,
                              hipStream_t stream) {
  (void)in_sizes; (void)n_in; (void)out_size; (void)ws_size;
  const float* x   = (const float*)d_in[0];   // (8, 64, 16, 32, 32) fp32
  const float* emb = (const float*)d_in[1];   // (512, 64) fp32
  float* out = (float*)d_out;

  char* ws = (char*)d_ws;
  short8* a1b  = (short8*)ws;                 // 65536 B
  half8*  eb3  = (half8*)(ws + 65536);        // 65536 B
  float*  norms = (float*)(ws + 131072);      // 2048 B

  prep_all<<<34, 256, 0, stream>>>(emb, a1b, eb3, norms);
  vq_main<<<512, 256, 0, stream>>>(x, a1b, eb3, norms, out);
}

// Round 14
// 38.127 us; speedup vs baseline: 3.2270x; 3.2270x over previous
//
#include <hip/hip_runtime.h>
#include <hip/hip_bf16.h>

typedef __attribute__((ext_vector_type(8))) short short8;
typedef __attribute__((ext_vector_type(4))) short short4v;
typedef __attribute__((ext_vector_type(8))) _Float16 half8;
typedef __attribute__((ext_vector_type(4))) float f32x4;

#define SPW 16384   // T*H*W spatial positions per batch
#define XST 72      // Xl row stride in shorts
#define RW  67      // Rf row stride in dwords
#define LOG2E 1.4426950408889634f

__device__ __forceinline__ float exp2_hw(float f) {
  return __builtin_amdgcn_exp2f(f);   // v_exp_f32 (base-2)
}

__device__ __forceinline__ short bf16s(float f) {
  union { __hip_bfloat16 h; short s; } u;
  u.h = __float2bfloat16(f);
  return u.s;
}

// ---------------- merged prep kernel ----------------
// a1b[(kt*64+lane)*2+s] : A-frags (16x16x32 bf16) of (-2*log2e)*E, pair contiguous
// eb3[(pr*64+lane)*4+m2]: B-frags (16x16x32 f16) of E for a kt-PAIR; slot i<4 ->
//                         k=(2pr)*16+4g+i, i>=4 -> k=(2pr+1)*16+4g+(i-4)
// norms[k]              : ||e_k||^2 * log2e
__global__ void prep_all(const float* __restrict__ emb, short8* __restrict__ a1b,
                         half8* __restrict__ eb3, float* __restrict__ norms) {
  const int f = blockIdx.x * 256 + threadIdx.x;
  if (f < 4096) {
    const int s = f & 1;
    const int lane = (f >> 1) & 63;
    const int kt = f >> 7;
    const int row = kt * 16 + (lane & 15);
    const int col0 = s * 32 + (lane >> 4) * 8;
    short8 v;
    #pragma unroll
    for (int i = 0; i < 8; ++i)
      v[i] = bf16s(-2.0f * LOG2E * emb[row * 64 + col0 + i]);
    a1b[f] = v;
  } else if (f < 8192) {
    const int e = f - 4096;
    const int m2 = e & 3;
    const int lane = (e >> 2) & 63;
    const int pr = e >> 8;               // kt-pair 0..15
    const int g = lane >> 4;
    const int d = m2 * 16 + (lane & 15);
    half8 v;
    #pragma unroll
    for (int i = 0; i < 8; ++i) {
      const int k = (i < 4) ? (pr * 32 + 4 * g + i) : (pr * 32 + 16 + 4 * g + (i - 4));
      v[i] = (_Float16)emb[k * 64 + d];
    }
    eb3[e] = v;
  } else if (f < 8704) {
    const int k = f - 8192;
    float acc = 0.f;
    #pragma unroll
    for (int d = 0; d < 64; ++d) { float e = emb[k * 64 + d]; acc += e * e; }
    norms[k] = acc * LOG2E;
  }
}

// per-iteration fragment set (register double-buffered)
struct Frags {
  short8 aA0, aA1, aB0, aB1;
  half8 e0, e1, e2, e3;
  float4 nvA, nvB;
};

__device__ __forceinline__ void ldfrag(Frags& f, const short8* __restrict__ a1b,
                                       const half8* __restrict__ eb3,
                                       const float* __restrict__ norms,
                                       int pr, int lane, int g) {
  const int ktA = pr * 2;
  f.nvA = *reinterpret_cast<const float4*>(&norms[ktA * 16 + g * 4]);
  f.nvB = *reinterpret_cast<const float4*>(&norms[ktA * 16 + 16 + g * 4]);
  const short8* ap = &a1b[(ktA * 64 + lane) * 2];
  f.aA0 = ap[0];
  f.aA1 = ap[1];
  f.aB0 = ap[128];             // ktB = ktA+1 -> +64*2 short8
  f.aB1 = ap[129];
  const half8* ep = &eb3[(pr * 64 + lane) * 4];   // 64B contiguous
  f.e0 = ep[0];
  f.e1 = ep[1];
  f.e2 = ep[2];
  f.e3 = ep[3];
}

__device__ __forceinline__ half8 make_pa(float p0, float p1, float p2, float p3,
                                         float p4, float p5, float p6, float p7) {
  const unsigned a = __builtin_bit_cast(unsigned, __builtin_amdgcn_cvt_pkrtz(p0, p1));
  const unsigned b = __builtin_bit_cast(unsigned, __builtin_amdgcn_cvt_pkrtz(p2, p3));
  const unsigned c = __builtin_bit_cast(unsigned, __builtin_amdgcn_cvt_pkrtz(p4, p5));
  const unsigned d = __builtin_bit_cast(unsigned, __builtin_amdgcn_cvt_pkrtz(p6, p7));
  const uint4 u = {a, b, c, d};
  return __builtin_bit_cast(half8, u);
}

__device__ __forceinline__ void compute_unit(const Frags& f, const short8 bx[4][2],
                                             f32x4 pacc[4][4], f32x4 dacc[4],
                                             const half8 ones) {
  #pragma unroll
  for (int j = 0; j < 4; ++j) {
    f32x4 zA = {f.nvA.x, f.nvA.y, f.nvA.z, f.nvA.w};   // norm term as C-init
    zA = __builtin_amdgcn_mfma_f32_16x16x32_bf16(f.aA0, bx[j][0], zA, 0, 0, 0);
    zA = __builtin_amdgcn_mfma_f32_16x16x32_bf16(f.aA1, bx[j][1], zA, 0, 0, 0);
    f32x4 zB = {f.nvB.x, f.nvB.y, f.nvB.z, f.nvB.w};
    zB = __builtin_amdgcn_mfma_f32_16x16x32_bf16(f.aB0, bx[j][0], zB, 0, 0, 0);
    zB = __builtin_amdgcn_mfma_f32_16x16x32_bf16(f.aB1, bx[j][1], zB, 0, 0, 0);
    const float p0 = exp2_hw(zA[0]);
    const float p1 = exp2_hw(zA[1]);
    const float p2 = exp2_hw(zA[2]);
    const float p3 = exp2_hw(zA[3]);
    const float p4 = exp2_hw(zB[0]);
    const float p5 = exp2_hw(zB[1]);
    const float p6 = exp2_hw(zB[2]);
    const float p7 = exp2_hw(zB[3]);
    const half8 pa = make_pa(p0, p1, p2, p3, p4, p5, p6, p7);
    pacc[j][0] = __builtin_amdgcn_mfma_f32_16x16x32_f16(pa, f.e0, pacc[j][0], 0, 0, 0);
    pacc[j][1] = __builtin_amdgcn_mfma_f32_16x16x32_f16(pa, f.e1, pacc[j][1], 0, 0, 0);
    pacc[j][2] = __builtin_amdgcn_mfma_f32_16x16x32_f16(pa, f.e2, pacc[j][2], 0, 0, 0);
    pacc[j][3] = __builtin_amdgcn_mfma_f32_16x16x32_f16(pa, f.e3, pacc[j][3], 0, 0, 0);
    // den: ones-MFMA -> dacc[j][r] = den[n=j*16+4g+r] (replicated over l15)
    dacc[j] = __builtin_amdgcn_mfma_f32_16x16x32_f16(pa, ones, dacc[j], 0, 0, 0);
  }
}

// ---------------- main kernel ----------------
// 4-wave blocks, 128 n-columns; wave (cg,kg) owns cols [cg*64,+64) x k [kg*256,+256)
// as 8 kt-pairs. logits(base2) = log2e*||e||^2 - 2log2e*(x.e); norm rides the
// mfma1 C-init; exp2 needs no max (|logit| tiny; softmax shift-invariance).
// mfma1 C-layout (col=l15,row=4g+r) == A-layout slots of mfma_f32_16x16x32_f16 ->
// P feeds mfma2 in-register. Frag stream explicitly double-buffered in registers
// ((256,2): 256-reg budget) so iteration p+1's loads fly during p's compute.
// NOTE (R13 lesson): register use is at the cliff -- do NOT add persistent state.
__global__ __launch_bounds__(256, 2) void vq_main(
    const float* __restrict__ x, const short8* __restrict__ a1b,
    const half8* __restrict__ eb3, const float* __restrict__ norms,
    float* __restrict__ out) {
  __shared__ __align__(16) char lds_raw[35840];
  short* Xl   = reinterpret_cast<short*>(lds_raw);            // [128][72] bf16 (staging)
  float* Rf   = reinterpret_cast<float*>(lds_raw);            // [128][67] f32 (epilogue)
  float* denl = reinterpret_cast<float*>(lds_raw + 34304);    // [2][128]
  float* rden = reinterpret_cast<float*>(lds_raw + 35328);    // [128]

  const int t = threadIdx.x;
  const int lane = t & 63;
  const int w = t >> 6;
  const int cg = w & 1;        // column group (64 cols)
  const int kg = w >> 1;       // k group (8 kt-pairs)
  const int l15 = lane & 15;
  const int g = lane >> 4;

  const int tile = blockIdx.x * 128;
  const int b = tile >> 14;
  const int off = tile & 16383;
  const float* xb = x + (size_t)b * (64 * SPW) + off;
  float* ob = out + (size_t)b * (64 * SPW) + off;

  // stage X tile: global [d][n] fp32 -> LDS [n][d] bf16; 256B contiguous per d-row
  {
    const int n0 = 4 * (t & 15);
    const int d0 = 4 * (t >> 4);
    #pragma unroll
    for (int h = 0; h < 2; ++h) {
      const int nb = h * 64 + n0;
      const float4 r0 = *reinterpret_cast<const float4*>(xb + (size_t)(d0 + 0) * SPW + nb);
      const float4 r1 = *reinterpret_cast<const float4*>(xb + (size_t)(d0 + 1) * SPW + nb);
      const float4 r2 = *reinterpret_cast<const float4*>(xb + (size_t)(d0 + 2) * SPW + nb);
      const float4 r3 = *reinterpret_cast<const float4*>(xb + (size_t)(d0 + 3) * SPW + nb);
      const short4v c0 = {bf16s(r0.x), bf16s(r1.x), bf16s(r2.x), bf16s(r3.x)};
      const short4v c1 = {bf16s(r0.y), bf16s(r1.y), bf16s(r2.y), bf16s(r3.y)};
      const short4v c2 = {bf16s(r0.z), bf16s(r1.z), bf16s(r2.z), bf16s(r3.z)};
      const short4v c3 = {bf16s(r0.w), bf16s(r1.w), bf16s(r2.w), bf16s(r3.w)};
      *reinterpret_cast<short4v*>(&Xl[(nb + 0) * XST + d0]) = c0;
      *reinterpret_cast<short4v*>(&Xl[(nb + 1) * XST + d0]) = c1;
      *reinterpret_cast<short4v*>(&Xl[(nb + 2) * XST + d0]) = c2;
      *reinterpret_cast<short4v*>(&Xl[(nb + 3) * XST + d0]) = c3;
    }
  }
  __syncthreads();

  // bx: matmul1 B-frags for this wave's 64 columns (32 VGPR)
  short8 bx[4][2];
  #pragma unroll
  for (int j = 0; j < 4; ++j) {
    const int base = (cg * 64 + j * 16 + l15) * XST + g * 8;
    bx[j][0] = *reinterpret_cast<const short8*>(&Xl[base]);
    bx[j][1] = *reinterpret_cast<const short8*>(&Xl[base + 32]);
  }
  __syncthreads();   // all Xl reads done before Rf (aliased) is written later

  f32x4 pacc[4][4];
  #pragma unroll
  for (int j = 0; j < 4; ++j)
    #pragma unroll
    for (int m2 = 0; m2 < 4; ++m2) pacc[j][m2] = f32x4{0.f, 0.f, 0.f, 0.f};
  f32x4 dacc[4];
  #pragma unroll
  for (int j = 0; j < 4; ++j) dacc[j] = f32x4{0.f, 0.f, 0.f, 0.f};
  const half8 ones = {(_Float16)1.f, (_Float16)1.f, (_Float16)1.f, (_Float16)1.f,
                      (_Float16)1.f, (_Float16)1.f, (_Float16)1.f, (_Float16)1.f};

  // main loop: explicit register double-buffer; issue p+1's loads before computing p
  const int prb = kg * 8;
  Frags fA, fB;
  ldfrag(fA, a1b, eb3, norms, prb + 0, lane, g);
  #pragma unroll
  for (int p2 = 0; p2 < 4; ++p2) {
    ldfrag(fB, a1b, eb3, norms, prb + 2 * p2 + 1, lane, g);
    compute_unit(fA, bx, pacc, dacc, ones);
    if (p2 < 3) ldfrag(fA, a1b, eb3, norms, prb + 2 * p2 + 2, lane, g);
    compute_unit(fB, bx, pacc, dacc, ones);
  }

  // den partials -> denl[kg][col]; dacc[j][r] = den[n=j*16+4g+r], uniform over l15
  if (l15 == 0) {
    #pragma unroll
    for (int j = 0; j < 4; ++j)
      #pragma unroll
      for (int r = 0; r < 4; ++r)
        denl[kg * 128 + cg * 64 + j * 16 + 4 * g + r] = dacc[j][r];
  }

  // phase A: kg==0 waves write their Num^T partial into Rf (Xl is dead)
  if (kg == 0) {
    #pragma unroll
    for (int j = 0; j < 4; ++j)
      #pragma unroll
      for (int m2 = 0; m2 < 4; ++m2)
        #pragma unroll
        for (int r = 0; r < 4; ++r)
          Rf[(cg * 64 + j * 16 + 4 * g + r) * RW + m2 * 16 + l15] = pacc[j][m2][r];
  }
  __syncthreads();   // denl complete; phase-A Rf writes complete

  // phase B: kg==1 waves accumulate; kg==0 threads (t<128) build reciprocal den
  if (kg == 1) {
    #pragma unroll
    for (int j = 0; j < 4; ++j)
      #pragma unroll
      for (int m2 = 0; m2 < 4; ++m2)
        #pragma unroll
        for (int r = 0; r < 4; ++r)
          Rf[(cg * 64 + j * 16 + 4 * g + r) * RW + m2 * 16 + l15] += pacc[j][m2][r];
  } else {
    rden[t & 127] = 1.0f / (denl[t & 127] + denl[128 + (t & 127)]);
  }
  __syncthreads();

  // phase C: cooperative store, 512B contiguous per d-row (32 lanes x float4)
  const int nq = t & 31;
  const int n = 4 * nq;
  const int dh = t >> 5;
  #pragma unroll
  for (int it = 0; it < 8; ++it) {
    const int d = it * 8 + dh;
    const float4 o = {Rf[(n + 0) * RW + d] * rden[n + 0],
                      Rf[(n + 1) * RW + d] * rden[n + 1],
                      Rf[(n + 2) * RW + d] * rden[n + 2],
                      Rf[(n + 3) * RW + d] * rden[n + 3]};
    *reinterpret_cast<float4*>(&ob[(size_t)d * SPW + n]) = o;
  }
}

extern "C" void kernel_launch(void* const* d_in, const int* in_sizes, int n_in,
                              void* d_out, int out_size, void* d_ws, size_t ws_size,
                              hipStream_t stream) {
  (void)in_sizes; (void)n_in; (void)out_size; (void)ws_size;
  const float* x   = (const float*)d_in[0];   // (8, 64, 16, 32, 32) fp32
  const float* emb = (const float*)d_in[1];   // (512, 64) fp32
  float* out = (float*)d_out;

  char* ws = (char*)d_ws;
  short8* a1b  = (short8*)ws;                 // 65536 B
  half8*  eb3  = (half8*)(ws + 65536);        // 65536 B
  float*  norms = (float*)(ws + 131072);      // 2048 B

  prep_all<<<34, 256, 0, stream>>>(emb, a1b, eb3, norms);
  vq_main<<<1024, 256, 0, stream>>>(x, a1b, eb3, norms, out);
}

// Round 15
// 37.357 us; speedup vs baseline: 3.2935x; 1.0206x over previous
//
#include <hip/hip_runtime.h>
#include <hip/hip_bf16.h>

typedef __attribute__((ext_vector_type(8))) short short8;
typedef __attribute__((ext_vector_type(4))) short short4v;
typedef __attribute__((ext_vector_type(8))) _Float16 half8;
typedef __attribute__((ext_vector_type(4))) float f32x4;

#define SPW 16384   // T*H*W spatial positions per batch
#define XST 72      // Xl row stride in shorts
#define RW  67      // Rf row stride in dwords
#define LOG2E 1.4426950408889634f

__device__ __forceinline__ float exp2_hw(float f) {
  return __builtin_amdgcn_exp2f(f);   // v_exp_f32 (base-2)
}

__device__ __forceinline__ short bf16s(float f) {
  union { __hip_bfloat16 h; short s; } u;
  u.h = __float2bfloat16(f);
  return u.s;
}

// ---------------- merged prep kernel ----------------
// a1b[(kt*64+lane)*2+s] : A-frags (16x16x32 bf16) of (-2*log2e)*E, pair contiguous
// eb3[(pr*64+lane)*4+m2]: B-frags (16x16x32 f16) of E for a kt-PAIR; slot i<4 ->
//                         k=(2pr)*16+4g+i, i>=4 -> k=(2pr+1)*16+4g+(i-4)
// norms[k]              : ||e_k||^2 * log2e
__global__ void prep_all(const float* __restrict__ emb, short8* __restrict__ a1b,
                         half8* __restrict__ eb3, float* __restrict__ norms) {
  const int f = blockIdx.x * 256 + threadIdx.x;
  if (f < 4096) {
    const int s = f & 1;
    const int lane = (f >> 1) & 63;
    const int kt = f >> 7;
    const int row = kt * 16 + (lane & 15);
    const int col0 = s * 32 + (lane >> 4) * 8;
    short8 v;
    #pragma unroll
    for (int i = 0; i < 8; ++i)
      v[i] = bf16s(-2.0f * LOG2E * emb[row * 64 + col0 + i]);
    a1b[f] = v;
  } else if (f < 8192) {
    const int e = f - 4096;
    const int m2 = e & 3;
    const int lane = (e >> 2) & 63;
    const int pr = e >> 8;               // kt-pair 0..15
    const int g = lane >> 4;
    const int d = m2 * 16 + (lane & 15);
    half8 v;
    #pragma unroll
    for (int i = 0; i < 8; ++i) {
      const int k = (i < 4) ? (pr * 32 + 4 * g + i) : (pr * 32 + 16 + 4 * g + (i - 4));
      v[i] = (_Float16)emb[k * 64 + d];
    }
    eb3[e] = v;
  } else if (f < 8704) {
    const int k = f - 8192;
    float acc = 0.f;
    #pragma unroll
    for (int d = 0; d < 64; ++d) { float e = emb[k * 64 + d]; acc += e * e; }
    norms[k] = acc * LOG2E;
  }
}

// per-iteration fragment set (register double-buffered)
struct Frags {
  short8 aA0, aA1, aB0, aB1;
  half8 e0, e1, e2, e3;
  float4 nvA, nvB;
};

__device__ __forceinline__ void ldfrag(Frags& f, const short8* __restrict__ a1b,
                                       const half8* __restrict__ eb3,
                                       const float* __restrict__ norms,
                                       int pr, int lane, int g) {
  const int ktA = pr * 2;
  f.nvA = *reinterpret_cast<const float4*>(&norms[ktA * 16 + g * 4]);
  f.nvB = *reinterpret_cast<const float4*>(&norms[ktA * 16 + 16 + g * 4]);
  const short8* ap = &a1b[(ktA * 64 + lane) * 2];
  f.aA0 = ap[0];
  f.aA1 = ap[1];
  f.aB0 = ap[128];             // ktB = ktA+1 -> +64*2 short8
  f.aB1 = ap[129];
  const half8* ep = &eb3[(pr * 64 + lane) * 4];   // 64B contiguous
  f.e0 = ep[0];
  f.e1 = ep[1];
  f.e2 = ep[2];
  f.e3 = ep[3];
}

__device__ __forceinline__ half8 make_pa(float p0, float p1, float p2, float p3,
                                         float p4, float p5, float p6, float p7) {
  const unsigned a = __builtin_bit_cast(unsigned, __builtin_amdgcn_cvt_pkrtz(p0, p1));
  const unsigned b = __builtin_bit_cast(unsigned, __builtin_amdgcn_cvt_pkrtz(p2, p3));
  const unsigned c = __builtin_bit_cast(unsigned, __builtin_amdgcn_cvt_pkrtz(p4, p5));
  const unsigned d = __builtin_bit_cast(unsigned, __builtin_amdgcn_cvt_pkrtz(p6, p7));
  const uint4 u = {a, b, c, d};
  return __builtin_bit_cast(half8, u);
}

__device__ __forceinline__ void compute_unit(const Frags& f, const short8 bx[4][2],
                                             f32x4 pacc[4][4], f32x4 dacc[4],
                                             const half8 ones) {
  #pragma unroll
  for (int j = 0; j < 4; ++j) {
    f32x4 zA = {f.nvA.x, f.nvA.y, f.nvA.z, f.nvA.w};   // norm term as C-init
    zA = __builtin_amdgcn_mfma_f32_16x16x32_bf16(f.aA0, bx[j][0], zA, 0, 0, 0);
    zA = __builtin_amdgcn_mfma_f32_16x16x32_bf16(f.aA1, bx[j][1], zA, 0, 0, 0);
    f32x4 zB = {f.nvB.x, f.nvB.y, f.nvB.z, f.nvB.w};
    zB = __builtin_amdgcn_mfma_f32_16x16x32_bf16(f.aB0, bx[j][0], zB, 0, 0, 0);
    zB = __builtin_amdgcn_mfma_f32_16x16x32_bf16(f.aB1, bx[j][1], zB, 0, 0, 0);
    const float p0 = exp2_hw(zA[0]);
    const float p1 = exp2_hw(zA[1]);
    const float p2 = exp2_hw(zA[2]);
    const float p3 = exp2_hw(zA[3]);
    const float p4 = exp2_hw(zB[0]);
    const float p5 = exp2_hw(zB[1]);
    const float p6 = exp2_hw(zB[2]);
    const float p7 = exp2_hw(zB[3]);
    const half8 pa = make_pa(p0, p1, p2, p3, p4, p5, p6, p7);
    pacc[j][0] = __builtin_amdgcn_mfma_f32_16x16x32_f16(pa, f.e0, pacc[j][0], 0, 0, 0);
    pacc[j][1] = __builtin_amdgcn_mfma_f32_16x16x32_f16(pa, f.e1, pacc[j][1], 0, 0, 0);
    pacc[j][2] = __builtin_amdgcn_mfma_f32_16x16x32_f16(pa, f.e2, pacc[j][2], 0, 0, 0);
    pacc[j][3] = __builtin_amdgcn_mfma_f32_16x16x32_f16(pa, f.e3, pacc[j][3], 0, 0, 0);
    // den: ones-MFMA -> dacc[j][r] = den[n=j*16+4g+r] (replicated over l15)
    dacc[j] = __builtin_amdgcn_mfma_f32_16x16x32_f16(pa, ones, dacc[j], 0, 0, 0);
  }
}

// ---------------- main kernel ----------------
// R14 (= R11, 38 us) + XOR-swizzled X staging. The [n][d] tile with 16B-aligned
// row stride is an inherent 8-way bank conflict on the staging ds_write_b64
// (4-row thread stride -> dword stride 144 = 16 mod 32); padding cannot fix it.
// Swizzle: LDS[n][d ^ sw(n)], sw(n) = ((n>>2)&7)<<3 shorts -- bijective per row,
// preserves 16B alignment of ds_write_b64 and ds_read_b128; residual <=2-way.
__global__ __launch_bounds__(256, 2) void vq_main(
    const float* __restrict__ x, const short8* __restrict__ a1b,
    const half8* __restrict__ eb3, const float* __restrict__ norms,
    float* __restrict__ out) {
  __shared__ __align__(16) char lds_raw[35840];
  short* Xl   = reinterpret_cast<short*>(lds_raw);            // [128][72] bf16 (staging)
  float* Rf   = reinterpret_cast<float*>(lds_raw);            // [128][67] f32 (epilogue)
  float* denl = reinterpret_cast<float*>(lds_raw + 34304);    // [2][128]
  float* rden = reinterpret_cast<float*>(lds_raw + 35328);    // [128]

  const int t = threadIdx.x;
  const int lane = t & 63;
  const int w = t >> 6;
  const int cg = w & 1;        // column group (64 cols)
  const int kg = w >> 1;       // k group (8 kt-pairs)
  const int l15 = lane & 15;
  const int g = lane >> 4;

  const int tile = blockIdx.x * 128;
  const int b = tile >> 14;
  const int off = tile & 16383;
  const float* xb = x + (size_t)b * (64 * SPW) + off;
  float* ob = out + (size_t)b * (64 * SPW) + off;

  // stage X tile: global [d][n] fp32 -> LDS [n][d^sw(n)] bf16; sw = ((n>>2)&7)<<3
  {
    const int n0 = 4 * (t & 15);
    const int d0 = 4 * (t >> 4);
    const int dsw = d0 ^ ((t & 7) << 3);   // (n0>>2)&7 == t&7, uniform over the 4 rows
    #pragma unroll
    for (int h = 0; h < 2; ++h) {
      const int nb = h * 64 + n0;          // h*64: (64>>2)&7 == 0 -> same sw
      const float4 r0 = *reinterpret_cast<const float4*>(xb + (size_t)(d0 + 0) * SPW + nb);
      const float4 r1 = *reinterpret_cast<const float4*>(xb + (size_t)(d0 + 1) * SPW + nb);
      const float4 r2 = *reinterpret_cast<const float4*>(xb + (size_t)(d0 + 2) * SPW + nb);
      const float4 r3 = *reinterpret_cast<const float4*>(xb + (size_t)(d0 + 3) * SPW + nb);
      const short4v c0 = {bf16s(r0.x), bf16s(r1.x), bf16s(r2.x), bf16s(r3.x)};
      const short4v c1 = {bf16s(r0.y), bf16s(r1.y), bf16s(r2.y), bf16s(r3.y)};
      const short4v c2 = {bf16s(r0.z), bf16s(r1.z), bf16s(r2.z), bf16s(r3.z)};
      const short4v c3 = {bf16s(r0.w), bf16s(r1.w), bf16s(r2.w), bf16s(r3.w)};
      *reinterpret_cast<short4v*>(&Xl[(nb + 0) * XST + dsw]) = c0;
      *reinterpret_cast<short4v*>(&Xl[(nb + 1) * XST + dsw]) = c1;
      *reinterpret_cast<short4v*>(&Xl[(nb + 2) * XST + dsw]) = c2;
      *reinterpret_cast<short4v*>(&Xl[(nb + 3) * XST + dsw]) = c3;
    }
  }
  __syncthreads();

  // bx: matmul1 B-frags for this wave's 64 columns (32 VGPR), swizzled reads
  short8 bx[4][2];
  #pragma unroll
  for (int j = 0; j < 4; ++j) {
    const int n = cg * 64 + j * 16 + l15;
    const int swn = ((n >> 2) & 7) << 3;
    const int base = n * XST;
    bx[j][0] = *reinterpret_cast<const short8*>(&Xl[base + ((g * 8) ^ swn)]);
    bx[j][1] = *reinterpret_cast<const short8*>(&Xl[base + ((32 + g * 8) ^ swn)]);
  }
  __syncthreads();   // all Xl reads done before Rf (aliased) is written later

  f32x4 pacc[4][4];
  #pragma unroll
  for (int j = 0; j < 4; ++j)
    #pragma unroll
    for (int m2 = 0; m2 < 4; ++m2) pacc[j][m2] = f32x4{0.f, 0.f, 0.f, 0.f};
  f32x4 dacc[4];
  #pragma unroll
  for (int j = 0; j < 4; ++j) dacc[j] = f32x4{0.f, 0.f, 0.f, 0.f};
  const half8 ones = {(_Float16)1.f, (_Float16)1.f, (_Float16)1.f, (_Float16)1.f,
                      (_Float16)1.f, (_Float16)1.f, (_Float16)1.f, (_Float16)1.f};

  // main loop: explicit register double-buffer; issue p+1's loads before computing p
  const int prb = kg * 8;
  Frags fA, fB;
  ldfrag(fA, a1b, eb3, norms, prb + 0, lane, g);
  #pragma unroll
  for (int p2 = 0; p2 < 4; ++p2) {
    ldfrag(fB, a1b, eb3, norms, prb + 2 * p2 + 1, lane, g);
    compute_unit(fA, bx, pacc, dacc, ones);
    if (p2 < 3) ldfrag(fA, a1b, eb3, norms, prb + 2 * p2 + 2, lane, g);
    compute_unit(fB, bx, pacc, dacc, ones);
  }

  // den partials -> denl[kg][col]; dacc[j][r] = den[n=j*16+4g+r], uniform over l15
  if (l15 == 0) {
    #pragma unroll
    for (int j = 0; j < 4; ++j)
      #pragma unroll
      for (int r = 0; r < 4; ++r)
        denl[kg * 128 + cg * 64 + j * 16 + 4 * g + r] = dacc[j][r];
  }

  // phase A: kg==0 waves write their Num^T partial into Rf (Xl is dead)
  if (kg == 0) {
    #pragma unroll
    for (int j = 0; j < 4; ++j)
      #pragma unroll
      for (int m2 = 0; m2 < 4; ++m2)
        #pragma unroll
        for (int r = 0; r < 4; ++r)
          Rf[(cg * 64 + j * 16 + 4 * g + r) * RW + m2 * 16 + l15] = pacc[j][m2][r];
  }
  __syncthreads();   // denl complete; phase-A Rf writes complete

  // phase B: kg==1 waves accumulate; kg==0 threads (t<128) build reciprocal den
  if (kg == 1) {
    #pragma unroll
    for (int j = 0; j < 4; ++j)
      #pragma unroll
      for (int m2 = 0; m2 < 4; ++m2)
        #pragma unroll
        for (int r = 0; r < 4; ++r)
          Rf[(cg * 64 + j * 16 + 4 * g + r) * RW + m2 * 16 + l15] += pacc[j][m2][r];
  } else {
    rden[t & 127] = 1.0f / (denl[t & 127] + denl[128 + (t & 127)]);
  }
  __syncthreads();

  // phase C: cooperative store, 512B contiguous per d-row (32 lanes x float4)
  const int nq = t & 31;
  const int n = 4 * nq;
  const int dh = t >> 5;
  #pragma unroll
  for (int it = 0; it < 8; ++it) {
    const int d = it * 8 + dh;
    const float4 o = {Rf[(n + 0) * RW + d] * rden[n + 0],
                      Rf[(n + 1) * RW + d] * rden[n + 1],
                      Rf[(n + 2) * RW + d] * rden[n + 2],
                      Rf[(n + 3) * RW + d] * rden[n + 3]};
    *reinterpret_cast<float4*>(&ob[(size_t)d * SPW + n]) = o;
  }
}

extern "C" void kernel_launch(void* const* d_in, const int* in_sizes, int n_in,
                              void* d_out, int out_size, void* d_ws, size_t ws_size,
                              hipStream_t stream) {
  (void)in_sizes; (void)n_in; (void)out_size; (void)ws_size;
  const float* x   = (const float*)d_in[0];   // (8, 64, 16, 32, 32) fp32
  const float* emb = (const float*)d_in[1];   // (512, 64) fp32
  float* out = (float*)d_out;

  char* ws = (char*)d_ws;
  short8* a1b  = (short8*)ws;                 // 65536 B
  half8*  eb3  = (half8*)(ws + 65536);        // 65536 B
  float*  norms = (float*)(ws + 131072);      // 2048 B

  prep_all<<<34, 256, 0, stream>>>(emb, a1b, eb3, norms);
  vq_main<<<1024, 256, 0, stream>>>(x, a1b, eb3, norms, out);
}